// Round 1
// baseline (3373.343 us; speedup 1.0000x reference)
//
#include <hip/hip_runtime.h>
#include <cstddef>

// Problem constants (from reference): L=8, N=16384, K=16, D_IN=D_OUT=256
#define NL 8
#define NN 16384
#define KC 16
#define DD 256

__device__ __forceinline__ float sigf(float x) { return 1.0f / (1.0f + expf(-x)); }

// C[M,N] = A[M,256] @ B[256,N] (+ bias if non-null)
// Grid: (N/64, M/64), block 256 threads, 4x4 micro-tile per thread.
__global__ __launch_bounds__(256) void gemm_k256(const float* __restrict__ A,
                                                 const float* __restrict__ B,
                                                 const float* __restrict__ bias,
                                                 float* __restrict__ C, int N) {
  __shared__ float As[16][64];      // As[k][m]
  __shared__ float Bs[16][68];      // Bs[k][n], padded
  const int bm = blockIdx.y << 6;
  const int bn = blockIdx.x << 6;
  const int tid = threadIdx.x;
  const int tm = (tid >> 4) << 2;   // 0..60
  const int tn = (tid & 15) << 2;   // 0..60
  // A-load mapping: m = tid/4 (0..63), k-quad = (tid%4)*4
  const int am = tid >> 2;
  const int ak = (tid & 3) << 2;
  // B-load mapping: k = tid/16 (0..15), n-quad = (tid%16)*4
  const int bk = tid >> 4;
  const int bq = (tid & 15) << 2;
  float acc[4][4] = {};
  for (int k0 = 0; k0 < 256; k0 += 16) {
    float4 av = *(const float4*)(A + (size_t)(bm + am) * 256 + (k0 + ak));
    float4 bv = *(const float4*)(B + (size_t)(k0 + bk) * N + (bn + bq));
    __syncthreads();   // previous iteration's LDS reads complete
    As[ak + 0][am] = av.x;
    As[ak + 1][am] = av.y;
    As[ak + 2][am] = av.z;
    As[ak + 3][am] = av.w;
    *(float4*)(&Bs[bk][bq]) = bv;
    __syncthreads();   // LDS tile populated
#pragma unroll
    for (int kk = 0; kk < 16; ++kk) {
      const float a0 = As[kk][tm + 0];
      const float a1 = As[kk][tm + 1];
      const float a2 = As[kk][tm + 2];
      const float a3 = As[kk][tm + 3];
      const float4 b = *(const float4*)(&Bs[kk][tn]);
      acc[0][0] += a0 * b.x; acc[0][1] += a0 * b.y; acc[0][2] += a0 * b.z; acc[0][3] += a0 * b.w;
      acc[1][0] += a1 * b.x; acc[1][1] += a1 * b.y; acc[1][2] += a1 * b.z; acc[1][3] += a1 * b.w;
      acc[2][0] += a2 * b.x; acc[2][1] += a2 * b.y; acc[2][2] += a2 * b.z; acc[2][3] += a2 * b.w;
      acc[3][0] += a3 * b.x; acc[3][1] += a3 * b.y; acc[3][2] += a3 * b.z; acc[3][3] += a3 * b.w;
    }
  }
  float4 bv = make_float4(0.f, 0.f, 0.f, 0.f);
  if (bias) bv = *(const float4*)(bias + bn + tn);
#pragma unroll
  for (int i = 0; i < 4; ++i) {
    float4 v;
    v.x = acc[i][0] + bv.x;
    v.y = acc[i][1] + bv.y;
    v.z = acc[i][2] + bv.z;
    v.w = acc[i][3] + bv.w;
    *(float4*)(C + (size_t)(bm + tm + i) * N + (bn + tn)) = v;
  }
}

// One node per block; thread d = one feature dim.
// Wx row layout: [Wf | Wi | Wu | Wo] (4 x 256).
// Gf[r,d]  = (h_prev @ U_f)[r,d];  Giuo[r,:] = (h_prev @ U_iuo)[r,:]  (768 wide)
__global__ __launch_bounds__(256) void node_level(
    const float* __restrict__ Wx,      // [NN,1024]
    const int* __restrict__ idx,       // [NN,16] this level
    const float* __restrict__ Gf,      // [NN,256]   (valid iff has_prev)
    const float* __restrict__ Giuo,    // [NN,768]   (valid iff has_prev)
    const float* __restrict__ c_prev,  // [NN,256]   (valid iff has_prev)
    float* __restrict__ h_out,         // [NN,256]
    float* __restrict__ c_out,         // [NN,256]
    int has_prev) {
  const int n = blockIdx.x;
  const int d = threadIdx.x;
  __shared__ int sidx[KC];
  if (d < KC) sidx[d] = idx[n * KC + d];
  __syncthreads();
  const float* wrow = Wx + (size_t)n * 1024;
  const float wf = wrow[d];
  float f = 0.f, si = 0.f, su = 0.f, so = 0.f;
  if (has_prev) {
    for (int k = 0; k < KC; ++k) {
      const int j = sidx[k];          // wave-uniform (from LDS)
      if (j <= 0) continue;           // -1 = masked, 0 = zero init row
      const size_t r = (size_t)(j - 1);
      const float ck = c_prev[r * DD + d];
      const float gf = Gf[r * DD + d];
      const float* gi = Giuo + r * (size_t)(3 * DD);
      f += sigf(wf + gf) * ck;        // per-child forget gate * child c
      si += gi[d];                    // Sum_k h_k @ U_iuo (by linearity)
      su += gi[DD + d];
      so += gi[2 * DD + d];
    }
  }
  const float iv = sigf(si + wrow[DD + d]);
  const float uv = tanhf(su + wrow[2 * DD + d]);
  const float ov = sigf(so + wrow[3 * DD + d]);
  const float nc = iv * uv + f;
  const float nh = ov * tanhf(nc);
  h_out[(size_t)n * DD + d] = nh;
  c_out[(size_t)n * DD + d] = nc;
}

extern "C" void kernel_launch(void* const* d_in, const int* in_sizes, int n_in,
                              void* d_out, int out_size, void* d_ws, size_t ws_size,
                              hipStream_t stream) {
  const float* tensor  = (const float*)d_in[0];  // [L,N,256]
  const int*   indices = (const int*)  d_in[1];  // [L,N,16]
  const float* W_w     = (const float*)d_in[2];  // [256,1024]
  const float* W_b     = (const float*)d_in[3];  // [1024]
  const float* U_f     = (const float*)d_in[4];  // [256,256]
  const float* U_iuo   = (const float*)d_in[5];  // [256,768]

  float* out   = (float*)d_out;
  float* res_h = out;                              // [L,N,256]
  float* res_c = out + (size_t)NL * NN * DD;       // [L,N,256]

  // Workspace: Wx [N,1024] + Gf [N,256] + Giuo [N,768] = N*2048 floats = 134 MB
  float* Wx   = (float*)d_ws;
  float* Gf   = Wx + (size_t)NN * 1024;
  float* Giuo = Gf + (size_t)NN * DD;

  for (int t = 0; t < NL; ++t) {
    const float* x = tensor + (size_t)t * NN * 256;
    gemm_k256<<<dim3(1024 / 64, NN / 64), 256, 0, stream>>>(x, W_w, W_b, Wx, 1024);
    const int has_prev = (t > 0) ? 1 : 0;
    const float* c_prev = nullptr;
    if (has_prev) {
      const float* h_prev = res_h + (size_t)(t - 1) * NN * DD;
      c_prev              = res_c + (size_t)(t - 1) * NN * DD;
      gemm_k256<<<dim3(256 / 64, NN / 64), 256, 0, stream>>>(h_prev, U_f, nullptr, Gf, 256);
      gemm_k256<<<dim3(768 / 64, NN / 64), 256, 0, stream>>>(h_prev, U_iuo, nullptr, Giuo, 768);
    }
    node_level<<<NN, 256, 0, stream>>>(Wx, indices + (size_t)t * NN * KC,
                                       Gf, Giuo, c_prev,
                                       res_h + (size_t)t * NN * DD,
                                       res_c + (size_t)t * NN * DD, has_prev);
  }
}

// Round 2
// 2464.327 us; speedup vs baseline: 1.3689x; 1.3689x over previous
//
#include <hip/hip_runtime.h>
#include <cstddef>

// L=8, N=16384, K=16, D_IN=D_OUT=256
#define NL 8
#define NN 16384
#define KC 16
#define DD 256

typedef __bf16 bf16x8 __attribute__((ext_vector_type(8)));
typedef float f32x4 __attribute__((ext_vector_type(4)));

__device__ __forceinline__ float sigf(float x) { return 1.0f / (1.0f + expf(-x)); }

// Build BcatT [1024 rows n][768 virtual-k] bf16, pre-transposed for gemm_bt.
// virtual-k: [0,256)=hi(B[k][n]); [256,512)=hi(B[k-256][n]); [512,768)=lo(B[k-512][n])
// (pairs with A virtual-k blocks [hi, lo, hi] -> hi*hi + lo*hi + hi*lo)
__global__ __launch_bounds__(256) void convert_weights(
    const float* __restrict__ W_w,   // [256,1024]
    const float* __restrict__ U_f,   // [256,256]
    const float* __restrict__ U_iuo, // [256,768]
    __bf16* __restrict__ WcatT,      // [1024][768]
    __bf16* __restrict__ UcatT) {    // [1024][768]
  const int n = blockIdx.x & 1023;
  const int k = threadIdx.x;
  float w;
  __bf16* dst;
  if (blockIdx.x < 1024) {
    w = W_w[k * 1024 + n];
    dst = WcatT + (size_t)n * 768;
  } else {
    // G columns: [0,256) = Gf (U_f), [256,1024) = Giuo (U_iuo)
    w = (n < 256) ? U_f[k * 256 + n] : U_iuo[k * 768 + (n - 256)];
    dst = UcatT + (size_t)n * 768;
  }
  __bf16 hi = (__bf16)w;
  __bf16 lo = (__bf16)(w - (float)hi);
  dst[k] = hi;
  dst[256 + k] = hi;
  dst[512 + k] = lo;
}

// fp32 -> (hi, lo) bf16 split, elementwise
__global__ __launch_bounds__(256) void convert_split(
    const float* __restrict__ src, __bf16* __restrict__ hi_out, __bf16* __restrict__ lo_out) {
  const size_t i = (size_t)blockIdx.x * 256 + threadIdx.x;
  const float v = src[i];
  const __bf16 hi = (__bf16)v;
  hi_out[i] = hi;
  lo_out[i] = (__bf16)(v - (float)hi);
}

// C[M,N] = splitfp32(A) @ B + bias, via bf16x3 MFMA emulation.
// A_hi/A_lo: [M,256] bf16 row-major. BT: [N][768] bf16 (catT layout above).
// grid (N/128, M/128), 256 threads (4 waves), 128x128 tile, 16x16x32 MFMA.
__global__ __launch_bounds__(256) void gemm_mfma(
    const __bf16* __restrict__ A_hi, const __bf16* __restrict__ A_lo,
    const __bf16* __restrict__ BT, const float* __restrict__ bias,
    float* __restrict__ C, int N) {
  __shared__ __align__(16) __bf16 As[128][32];
  __shared__ __align__(16) __bf16 Bs[128][32];
  const int tid = threadIdx.x;
  const int bm = blockIdx.y << 7;
  const int bn = blockIdx.x << 7;
  const int w = tid >> 6;
  const int lane = tid & 63;
  const int r = lane & 15;      // fragment row (A m / B n / C col)
  const int q = lane >> 4;      // k-quad
  const int wm = (w & 1) << 6;  // wave tile: 64x64
  const int wn = (w >> 1) << 6;
  const int sr0 = tid >> 2;     // staging row 0..63
  const int sk = (tid & 3) << 3;// staging k-offset (bf16 elems): 0,8,16,24

  f32x4 acc[4][4];
#pragma unroll
  for (int i = 0; i < 4; ++i)
#pragma unroll
    for (int j = 0; j < 4; ++j) {
      acc[i][j][0] = 0.f; acc[i][j][1] = 0.f; acc[i][j][2] = 0.f; acc[i][j][3] = 0.f;
    }

  for (int kb = 0; kb < 24; ++kb) {
    const __bf16* Asrc;
    int koff;
    if (kb < 8)       { Asrc = A_hi; koff = kb << 5; }
    else if (kb < 16) { Asrc = A_lo; koff = (kb - 8) << 5; }
    else              { Asrc = A_hi; koff = (kb - 16) << 5; }
    const int bkoff = kb << 5;
    // global -> regs (16B per load)
    uint4 a0 = *(const uint4*)(Asrc + (size_t)(bm + sr0) * 256 + koff + sk);
    uint4 a1 = *(const uint4*)(Asrc + (size_t)(bm + sr0 + 64) * 256 + koff + sk);
    uint4 b0 = *(const uint4*)(BT + (size_t)(bn + sr0) * 768 + bkoff + sk);
    uint4 b1 = *(const uint4*)(BT + (size_t)(bn + sr0 + 64) * 768 + bkoff + sk);
    __syncthreads();  // previous iter's LDS reads done
    *(uint4*)(&As[sr0][sk]) = a0;
    *(uint4*)(&As[sr0 + 64][sk]) = a1;
    *(uint4*)(&Bs[sr0][sk]) = b0;
    *(uint4*)(&Bs[sr0 + 64][sk]) = b1;
    __syncthreads();  // tile ready
    bf16x8 af[4], bfr[4];
#pragma unroll
    for (int i = 0; i < 4; ++i) af[i] = *(const bf16x8*)(&As[wm + i * 16 + r][q << 3]);
#pragma unroll
    for (int j = 0; j < 4; ++j) bfr[j] = *(const bf16x8*)(&Bs[wn + j * 16 + r][q << 3]);
#pragma unroll
    for (int i = 0; i < 4; ++i)
#pragma unroll
      for (int j = 0; j < 4; ++j)
        acc[i][j] = __builtin_amdgcn_mfma_f32_16x16x32_bf16(af[i], bfr[j], acc[i][j], 0, 0, 0);
  }

  // epilogue: C/D layout col = lane&15 (=r), row = q*4 + reg
  float bv[4] = {0.f, 0.f, 0.f, 0.f};
  if (bias) {
#pragma unroll
    for (int j = 0; j < 4; ++j) bv[j] = bias[bn + wn + j * 16 + r];
  }
#pragma unroll
  for (int i = 0; i < 4; ++i) {
    const int row0 = bm + wm + i * 16 + (q << 2);
#pragma unroll
    for (int j = 0; j < 4; ++j) {
      const int col = bn + wn + j * 16 + r;
#pragma unroll
      for (int t2 = 0; t2 < 4; ++t2)
        C[(size_t)(row0 + t2) * N + col] = acc[i][j][t2] + bv[j];
    }
  }
}

// One node per block; thread d = one feature dim.
// Wx row: [Wf | Wi | Wu | Wo]. G row: [Gf(256) | Gi(256) | Gu(256) | Go(256)]
__global__ __launch_bounds__(256) void node_level(
    const float* __restrict__ Wx,      // [NN,1024]
    const int* __restrict__ idx,       // [NN,16]
    const float* __restrict__ G,       // [NN,1024] (valid iff has_prev)
    const float* __restrict__ c_prev,  // [NN,256]  (valid iff has_prev)
    float* __restrict__ h_out,         // [NN,256]
    float* __restrict__ c_out,         // [NN,256]
    __bf16* __restrict__ h_hi,         // [NN,256] bf16 split for next level
    __bf16* __restrict__ h_lo,
    int has_prev) {
  const int n = blockIdx.x;
  const int d = threadIdx.x;
  __shared__ int sidx[KC];
  if (d < KC) sidx[d] = idx[n * KC + d];
  __syncthreads();
  const float* wrow = Wx + (size_t)n * 1024;
  const float wf = wrow[d];
  float f = 0.f, si = 0.f, su = 0.f, so = 0.f;
  if (has_prev) {
    for (int k = 0; k < KC; ++k) {
      const int j = sidx[k];          // wave-uniform (LDS)
      if (j <= 0) continue;           // -1 masked, 0 = zero init row
      const size_t rr = (size_t)(j - 1);
      const float* grow = G + rr * 1024;
      const float ck = c_prev[rr * DD + d];
      f += sigf(wf + grow[d]) * ck;
      si += grow[256 + d];
      su += grow[512 + d];
      so += grow[768 + d];
    }
  }
  const float iv = sigf(si + wrow[DD + d]);
  const float uv = tanhf(su + wrow[2 * DD + d]);
  const float ov = sigf(so + wrow[3 * DD + d]);
  const float nc = iv * uv + f;
  const float nh = ov * tanhf(nc);
  h_out[(size_t)n * DD + d] = nh;
  c_out[(size_t)n * DD + d] = nc;
  const __bf16 hh = (__bf16)nh;
  h_hi[(size_t)n * DD + d] = hh;
  h_lo[(size_t)n * DD + d] = (__bf16)(nh - (float)hh);
}

extern "C" void kernel_launch(void* const* d_in, const int* in_sizes, int n_in,
                              void* d_out, int out_size, void* d_ws, size_t ws_size,
                              hipStream_t stream) {
  const float* tensor  = (const float*)d_in[0];  // [L,N,256]
  const int*   indices = (const int*)  d_in[1];  // [L,N,16]
  const float* W_w     = (const float*)d_in[2];  // [256,1024]
  const float* W_b     = (const float*)d_in[3];  // [1024]
  const float* U_f     = (const float*)d_in[4];  // [256,256]
  const float* U_iuo   = (const float*)d_in[5];  // [256,768]

  float* out   = (float*)d_out;
  float* res_h = out;                            // [L,N,256]
  float* res_c = out + (size_t)NL * NN * DD;     // [L,N,256]

  // workspace carve (all 16B-aligned)
  char* p = (char*)d_ws;
  __bf16* WcatT = (__bf16*)p; p += (size_t)1024 * 768 * 2;   // 1.5MB
  __bf16* UcatT = (__bf16*)p; p += (size_t)1024 * 768 * 2;   // 1.5MB
  __bf16* x_hi  = (__bf16*)p; p += (size_t)NN * 256 * 2;     // 8MB
  __bf16* x_lo  = (__bf16*)p; p += (size_t)NN * 256 * 2;     // 8MB
  __bf16* h_hi  = (__bf16*)p; p += (size_t)NN * 256 * 2;     // 8MB
  __bf16* h_lo  = (__bf16*)p; p += (size_t)NN * 256 * 2;     // 8MB
  float*  Wx    = (float*)p;  p += (size_t)NN * 1024 * 4;    // 64MB
  float*  G     = (float*)p;  p += (size_t)NN * 1024 * 4;    // 64MB

  convert_weights<<<2048, 256, 0, stream>>>(W_w, U_f, U_iuo, WcatT, UcatT);

  for (int t = 0; t < NL; ++t) {
    const float* x = tensor + (size_t)t * NN * 256;
    convert_split<<<NN, 256, 0, stream>>>(x, x_hi, x_lo);
    gemm_mfma<<<dim3(8, NN / 128), 256, 0, stream>>>(x_hi, x_lo, WcatT, W_b, Wx, 1024);
    const int has_prev = (t > 0) ? 1 : 0;
    const float* c_prev = nullptr;
    if (has_prev) {
      c_prev = res_c + (size_t)(t - 1) * NN * DD;
      // G = h_prev @ [U_f | U_iuo]  (h_hi/h_lo written by previous level's node kernel)
      gemm_mfma<<<dim3(8, NN / 128), 256, 0, stream>>>(h_hi, h_lo, UcatT, nullptr, G, 1024);
    }
    node_level<<<NN, 256, 0, stream>>>(Wx, indices + (size_t)t * NN * KC,
                                       G, c_prev,
                                       res_h + (size_t)t * NN * DD,
                                       res_c + (size_t)t * NN * DD,
                                       h_hi, h_lo, has_prev);
  }
}